// Round 7
// baseline (283.484 us; speedup 1.0000x reference)
//
#include <hip/hip_runtime.h>
#include <hip/hip_bf16.h>
#include <hip/hip_fp16.h>
#include <math.h>

// ---------------------------------------------------------------------------
// 2-layer GAT (PyG GATConv) + global mean pool on MI355X. float32 in/out.
// R25 -> R26:
//  - Discovery: harness poisons the 256MiB workspace each iter (44us fill);
//    it was the hidden #2. gat2 split reverted (+3us cost, no more info).
//  - k_gat2: FEATURE-SPLIT two-pass. hC stored as two contiguous planes
//    hC_lo[n][32], hC_hi[n][32] (written by lin2). Each gat2 pass gathers
//    from a 3.2MB plane that is L2-RESIDENT per XCD (4MB L2), eliminating
//    the ~98MB of L2-thrash refills (FETCH was 15x the 6.4MB table).
//    Quad-split: 4 lanes x 8B per edge row-half, 16 edges/step.
//    dn/inv computed in pass A, reused in pass B.
// All else identical to R25 (scatt int2+LDS sort, bgat1 praw single-pass).
// ---------------------------------------------------------------------------

__device__ __forceinline__ float leaky(float x) { return x >= 0.f ? x : 0.2f * x; }
__device__ __forceinline__ int iclamp(int v, int lo, int hi) {
  return v < lo ? lo : (v > hi ? hi : v);
}
__device__ __forceinline__ unsigned char f8(float v) {
  return (unsigned char)(__builtin_amdgcn_cvt_pk_fp8_f32(v, v, 0, false) & 0xff);
}
__device__ __forceinline__ float hlo(unsigned w) {
  __half2 h = *(__half2*)&w; return __half2float(h.x);
}
__device__ __forceinline__ float hhi(unsigned w) {
  __half2 h = *(__half2*)&w; return __half2float(h.y);
}

typedef __attribute__((ext_vector_type(8))) _Float16 f16x8;
typedef __attribute__((ext_vector_type(4))) float f32x4;
typedef __attribute__((ext_vector_type(2))) float f32x2;

#define NBUCK 1024
#define BSHIFT 7          // 128 nodes per bucket; valid for n <= 131072
#define BCAP 4608         // per-bucket capacity: mean 4096 + 8 sigma (n=100k)
#define CSRSZ (NBUCK * BCAP)
#define MAXR 8            // max staged edges per thread in scatter
#define SCAP (MAXR * 1024)

// K-A: fused scatter + att1. Blocks [0,NBK): scatter; [NBK, NBK+natt): att1.
__global__ __launch_bounds__(1024, 8) void k_scatt(
    const int* __restrict__ ei, int E, int n, int* __restrict__ bcur,
    unsigned* __restrict__ pairs,
    const float* __restrict__ x, const float* __restrict__ W1,
    const float* __restrict__ att_src1, const float* __restrict__ att_dst1,
    uint4* __restrict__ xs, float* __restrict__ a_dst1, int NBK) {
  __shared__ int h[NBUCK];                 // histogram counts
  __shared__ int cur[NBUCK];               // local placement cursor
  __shared__ int gofs[NBUCK];              // global_base - local_offset
  __shared__ int wtot[16];                 // per-wave scan totals
  __shared__ int htot;                     // grand total
  __shared__ unsigned sstage[SCAP];        // bucket-sorted entries (32KB)
  __shared__ unsigned short sbkt[SCAP];    // bucket id per entry (16KB)
  __shared__ float W1s[256];
  __shared__ float as1[64];
  __shared__ float ad1[64];
  int t = threadIdx.x;
  if (blockIdx.x >= NBK) {
    // ---- att1 part: 64 nodes per block, 16 lanes per node ----
    if (t < 256) W1s[t] = W1[t];
    else if (t >= 256 && t < 320) as1[t - 256] = att_src1[t - 256];
    else if (t >= 320 && t < 384) ad1[t - 320] = att_dst1[t - 320];
    __syncthreads();
    int grp = t >> 4, sub = t & 15;
    int node = (blockIdx.x - NBK) * 64 + grp;
    if (node >= n) return;
    float4 xr = ((const float4*)x)[node];
    float vs = 0.f, vd = 0.f;
    #pragma unroll
    for (int i = 0; i < 4; ++i) {
      int c = sub * 4 + i;
      float hv = xr.x * W1s[c] + xr.y * W1s[64 + c] + xr.z * W1s[128 + c] + xr.w * W1s[192 + c];
      vs = fmaf(hv, as1[c], vs);
      vd = fmaf(hv, ad1[c], vd);
    }
    #pragma unroll
    for (int m = 4; m >= 1; m >>= 1) { vs += __shfl_xor(vs, m); vd += __shfl_xor(vd, m); }
    int wl = t & 63;                       // lane within wave
    float vs1 = __shfl(vs, (wl & 48) + 8); // head1 total (group base + 8)
    float vd1 = __shfl(vd, (wl & 48) + 8);
    if (sub == 0) {
      __half2 x01 = __float22half2_rn(make_float2(xr.x, xr.y));
      __half2 x23 = __float22half2_rn(make_float2(xr.z, xr.w));
      uint4 rec;
      rec.x = *(unsigned*)&x01;
      rec.y = *(unsigned*)&x23;
      rec.z = __float_as_uint(vs);
      rec.w = __float_as_uint(vs1);
      xs[node] = rec;
      ((float2*)a_dst1)[node] = make_float2(vd, vd1);
    }
    return;
  }
  // ---- scatter part ----
  h[t] = 0;
  __syncthreads();
  int chunk = (E + NBK - 1) / NBK;
  chunk = (chunk + 1) & ~1;                // even -> beg stays 8B-aligned
  int beg = blockIdx.x * chunk;
  int end = beg + chunk; if (end > E) end = E;
  unsigned pR[MAXR];
  unsigned short bR[MAXR];
  int cntr = 0;
  for (int i = beg + 2 * t; i < end && cntr < MAXR; i += 2048) {
    if (i + 1 < end) {
      int2 sv = *(const int2*)(ei + i);
      int2 dv = *(const int2*)(ei + E + i);
      {
        int s = iclamp(sv.x, 0, n - 1);
        int d = iclamp(dv.x, 0, n - 1);
        int bkt = d >> BSHIFT;
        pR[cntr] = ((unsigned)(d & 127) << 25) | (unsigned)s;
        bR[cntr] = (unsigned short)bkt;
        atomicAdd(&h[bkt], 1);
        ++cntr;
      }
      if (cntr < MAXR) {
        int s = iclamp(sv.y, 0, n - 1);
        int d = iclamp(dv.y, 0, n - 1);
        int bkt = d >> BSHIFT;
        pR[cntr] = ((unsigned)(d & 127) << 25) | (unsigned)s;
        bR[cntr] = (unsigned short)bkt;
        atomicAdd(&h[bkt], 1);
        ++cntr;
      }
    } else {
      int s = iclamp(ei[i], 0, n - 1);
      int d = iclamp(ei[E + i], 0, n - 1);
      int bkt = d >> BSHIFT;
      pR[cntr] = ((unsigned)(d & 127) << 25) | (unsigned)s;
      bR[cntr] = (unsigned short)bkt;
      atomicAdd(&h[bkt], 1);
      ++cntr;
    }
  }
  __syncthreads();
  int v = h[t];
  // hierarchical inclusive scan: wave-level shfl_up + 16-wave combine
  int lanei = t & 63, wid = t >> 6;
  int sc = v;
  #pragma unroll
  for (int ofs = 1; ofs < 64; ofs <<= 1) {
    int u = __shfl_up(sc, ofs);
    if (lanei >= ofs) sc += u;
  }
  if (lanei == 63) wtot[wid] = sc;
  __syncthreads();
  if (wid == 0 && lanei < 16) {
    int wv = wtot[lanei];
    int s2 = wv;
    #pragma unroll
    for (int ofs = 1; ofs < 16; ofs <<= 1) {
      int u = __shfl_up(s2, ofs);
      if (lanei >= ofs) s2 += u;
    }
    wtot[lanei] = s2 - wv;          // exclusive per-wave offset
  }
  __syncthreads();
  int incl = sc + wtot[wid];        // inclusive scan over 1024 buckets
  int loff = incl - v;              // exclusive local offset
  cur[t] = loff;
  gofs[t] = t * BCAP + (v ? atomicAdd(&bcur[t], v) : 0) - loff;
  if (t == 1023) htot = incl;
  __syncthreads();
  // place entries bucket-sorted into LDS
  for (int k = 0; k < cntr; ++k) {
    int b = bR[k];
    int lpos = atomicAdd(&cur[b], 1);
    sstage[lpos] = pR[k];
    sbkt[lpos] = (unsigned short)b;
  }
  __syncthreads();
  // coalesced flush: consecutive i in same bucket -> consecutive addresses
  int total = htot;
  for (int i = t; i < total; i += 1024) {
    int b = sbkt[i];
    int pos = gofs[b] + i;
    if (pos >= b * BCAP && pos < (b + 1) * BCAP) pairs[pos] = sstage[i];
  }
}

// K-B: fused per-bucket CSR build + layer-1 GAT. One block per bucket.
__global__ __launch_bounds__(256) void k_bgat1(
    const unsigned* __restrict__ pairs, const int* __restrict__ bcur,
    const uint4* __restrict__ xs, const float* __restrict__ W1,
    const float* __restrict__ a_dst1, const float* __restrict__ bias1,
    int* __restrict__ rowbeg, int* __restrict__ rowend, int* __restrict__ csr,
    __half* __restrict__ hB, int n) {
  __shared__ int lcsr[BCAP];
  __shared__ int praw[BCAP];
  __shared__ int sh[128];
  __shared__ int cur[128];
  __shared__ int lrb[128];
  __shared__ int lre[128];
  __shared__ int wt[2];
  __shared__ float W1s[256];
  int t = threadIdx.x;
  W1s[t] = W1[t];
  int b = blockIdx.x;
  int node0 = b << BSHIFT;
  if (node0 >= n) return;  // uniform per block
  int base = b * BCAP;
  int cnt = iclamp(bcur[b], 0, BCAP);
  if (t < 128) sh[t] = 0;
  __syncthreads();
  // single global pass: stage + histogram
  for (int i = t; i < cnt; i += 256) {
    int pv = (int)pairs[base + i];
    praw[i] = pv;
    atomicAdd(&sh[((unsigned)pv) >> 25], 1);
  }
  __syncthreads();
  // hierarchical scan over 128 counts: waves 0,1 via shfl_up + combine
  int v = (t < 128) ? sh[t] : 0;
  int lanei = t & 63, wid = t >> 6;
  int sc = v;
  if (wid < 2) {
    #pragma unroll
    for (int ofs = 1; ofs < 64; ofs <<= 1) {
      int u = __shfl_up(sc, ofs);
      if (lanei >= ofs) sc += u;
    }
    if (lanei == 63) wt[wid] = sc;
  }
  __syncthreads();
  if (t < 128) {
    int off = sc + ((wid == 1) ? wt[0] : 0) - v;  // exclusive
    cur[t] = off;
    lrb[t] = off;
    lre[t] = off + v;
    int node = node0 + t;
    if (node < n) {
      rowbeg[node] = base + off;
      rowend[node] = base + off + v;
    }
  }
  __syncthreads();
  // placement from LDS
  for (int i = t; i < cnt; i += 256) {
    unsigned p = (unsigned)praw[i];
    int l = p >> 25;
    int r = atomicAdd(&cur[l], 1);
    if (r >= 0 && r < BCAP) lcsr[r] = (int)(p & 0x1ffffffu);
  }
  __syncthreads();
  for (int i = t; i < cnt; i += 256)
    csr[base + i] = lcsr[i];    // coalesced flush (csr aliases pairs buffer)
  // ---- gat1 phase: 4 waves x 4 nodes x 16 lanes; 8 rounds = 128 nodes ----
  int wave = t >> 6, lane = t & 63;
  int nd = (lane >> 4), sub = lane & 15;
  for (int rnd = 0; rnd < 8; ++rnd) {
    int nodeLocal = rnd * 16 + wave * 4 + nd;
    int node = node0 + nodeLocal;
    bool valid = node < n;
    int nc = valid ? node : 0;
    int ebeg = valid ? lrb[nodeLocal] : 0;
    int eend = valid ? lre[nodeLocal] : 0;
    ebeg = iclamp(ebeg, 0, BCAP);
    eend = iclamp(eend, ebeg, BCAP);
    float2 ad = ((const float2*)a_dst1)[nc];
    uint4 rs = xs[nc];       // self-loop record: prefetch (independent)
    float A0 = 0.f, A1 = 0.f, A2 = 0.f, A3 = 0.f, dn0 = 0.f;
    float B0 = 0.f, B1 = 0.f, B2 = 0.f, B3 = 0.f, dn1 = 0.f;
    int e = ebeg + sub;
    for (; e + 16 < eend; e += 32) {
      int sa = iclamp(lcsr[e], 0, n - 1);
      int sb = iclamp(lcsr[e + 16], 0, n - 1);
      uint4 ra = xs[sa];
      uint4 rb = xs[sb];
      float ea0 = __expf(leaky(__uint_as_float(ra.z) + ad.x));
      float ea1 = __expf(leaky(__uint_as_float(ra.w) + ad.y));
      float eb0 = __expf(leaky(__uint_as_float(rb.z) + ad.x));
      float eb1 = __expf(leaky(__uint_as_float(rb.w) + ad.y));
      dn0 += ea0 + eb0; dn1 += ea1 + eb1;
      float xa0 = hlo(ra.x), xa1 = hhi(ra.x), xa2 = hlo(ra.y), xa3 = hhi(ra.y);
      float xb0 = hlo(rb.x), xb1 = hhi(rb.x), xb2 = hlo(rb.y), xb3 = hhi(rb.y);
      A0 = fmaf(ea0, xa0, A0); A1 = fmaf(ea0, xa1, A1);
      A2 = fmaf(ea0, xa2, A2); A3 = fmaf(ea0, xa3, A3);
      B0 = fmaf(ea1, xa0, B0); B1 = fmaf(ea1, xa1, B1);
      B2 = fmaf(ea1, xa2, B2); B3 = fmaf(ea1, xa3, B3);
      A0 = fmaf(eb0, xb0, A0); A1 = fmaf(eb0, xb1, A1);
      A2 = fmaf(eb0, xb2, A2); A3 = fmaf(eb0, xb3, A3);
      B0 = fmaf(eb1, xb0, B0); B1 = fmaf(eb1, xb1, B1);
      B2 = fmaf(eb1, xb2, B2); B3 = fmaf(eb1, xb3, B3);
    }
    if (e < eend) {
      int s = iclamp(lcsr[e], 0, n - 1);
      uint4 rr = xs[s];
      float ex0 = __expf(leaky(__uint_as_float(rr.z) + ad.x));
      float ex1 = __expf(leaky(__uint_as_float(rr.w) + ad.y));
      dn0 += ex0; dn1 += ex1;
      float x0 = hlo(rr.x), x1 = hhi(rr.x), x2 = hlo(rr.y), x3 = hhi(rr.y);
      A0 = fmaf(ex0, x0, A0); A1 = fmaf(ex0, x1, A1);
      A2 = fmaf(ex0, x2, A2); A3 = fmaf(ex0, x3, A3);
      B0 = fmaf(ex1, x0, B0); B1 = fmaf(ex1, x1, B1);
      B2 = fmaf(ex1, x2, B2); B3 = fmaf(ex1, x3, B3);
    }
    bool lo = (sub < 8);
    float C0, C1, C2, C3, dnC, sA, sB;
    sA = __shfl_xor(A0, 8); sB = __shfl_xor(B0, 8); C0 = lo ? A0 + sA : B0 + sB;
    sA = __shfl_xor(A1, 8); sB = __shfl_xor(B1, 8); C1 = lo ? A1 + sA : B1 + sB;
    sA = __shfl_xor(A2, 8); sB = __shfl_xor(B2, 8); C2 = lo ? A2 + sA : B2 + sB;
    sA = __shfl_xor(A3, 8); sB = __shfl_xor(B3, 8); C3 = lo ? A3 + sA : B3 + sB;
    sA = __shfl_xor(dn0, 8); sB = __shfl_xor(dn1, 8); dnC = lo ? dn0 + sA : dn1 + sB;
    #pragma unroll
    for (int m = 4; m >= 1; m >>= 1) {
      C0 += __shfl_xor(C0, m); C1 += __shfl_xor(C1, m);
      C2 += __shfl_xor(C2, m); C3 += __shfl_xor(C3, m);
      dnC += __shfl_xor(dnC, m);
    }
    // self loop from the prefetched record
    float exs = __expf(leaky(__uint_as_float(lo ? rs.z : rs.w) + (lo ? ad.x : ad.y)));
    dnC += exs;
    float xs0 = hlo(rs.x), xs1 = hhi(rs.x), xs2 = hlo(rs.y), xs3 = hhi(rs.y);
    C0 = fmaf(exs, xs0, C0); C1 = fmaf(exs, xs1, C1);
    C2 = fmaf(exs, xs2, C2); C3 = fmaf(exs, xs3, C3);
    float inv = 1.0f / (dnC + 1e-16f);
    if (valid) {
      int f0 = sub * 4;
      float vv[4];
      #pragma unroll
      for (int i = 0; i < 4; ++i) {
        int f = f0 + i;
        float accv = C0 * W1s[f] + C1 * W1s[64 + f] + C2 * W1s[128 + f] + C3 * W1s[192 + f];
        float vx = accv * inv + bias1[f];
        vv[i] = vx > 0.f ? vx : expm1f(vx);  // ELU (alpha=1)
      }
      __half2 h01 = __float22half2_rn(make_float2(vv[0], vv[1]));
      __half2 h23 = __float22half2_rn(make_float2(vv[2], vv[3]));
      uint2 pk;
      pk.x = *(unsigned*)&h01;
      pk.y = *(unsigned*)&h23;
      *(uint2*)(hB + (size_t)node * 64 + f0) = pk;
    }
  }
}

// K6 (MFMA fp16): hC = fp8(hB @ W2) into TWO planes, plus a_src2/a_dst2.
__global__ __launch_bounds__(256) void k_lin2(
    const __half* __restrict__ hB, const float* __restrict__ W2,
    const float* __restrict__ att_src2, const float* __restrict__ att_dst2,
    float* __restrict__ a_src2, float* __restrict__ a_dst2,
    unsigned char* __restrict__ hC, int n) {
  __shared__ __attribute__((aligned(16))) _Float16 Whi[64 * 72];
  __shared__ __attribute__((aligned(16))) _Float16 Wlo[64 * 72];
  int t = threadIdx.x;
  for (int i = t; i < 4096; i += 256) {
    int k = i >> 6, col = i & 63;
    float w = W2[i];
    _Float16 hi = (_Float16)w;
    _Float16 lo = (_Float16)(w - (float)hi);
    Whi[col * 72 + k] = hi;
    Wlo[col * 72 + k] = lo;
  }
  __syncthreads();
  int wave = t >> 6, lane = t & 63;
  int quad = lane >> 4, c = lane & 15;
  float as2[4], ad2[4];
  #pragma unroll
  for (int tt = 0; tt < 4; ++tt) {
    as2[tt] = att_src2[tt * 16 + c];
    ad2[tt] = att_dst2[tt * 16 + c];
  }
  size_t plane = (size_t)n * 32;
  for (int it = 0; it < 4; ++it) {
    int m0 = blockIdx.x * 256 + wave * 64 + it * 16;
    if (m0 >= n) break;
    int mrow = m0 + c; if (mrow > n - 1) mrow = n - 1;
    const _Float16* hrow = (const _Float16*)(hB + (size_t)mrow * 64);
    f16x8 a0 = *(const f16x8*)(hrow + quad * 8);
    f16x8 a1 = *(const f16x8*)(hrow + 32 + quad * 8);
    f32x4 zero = {0.f, 0.f, 0.f, 0.f};
    f32x4 acc[4] = {zero, zero, zero, zero};
    #pragma unroll
    for (int tt = 0; tt < 4; ++tt) {
      int nn = tt * 16 + c;
      const _Float16* wh = &Whi[nn * 72];
      const _Float16* wl = &Wlo[nn * 72];
      f16x8 bh0 = *(const f16x8*)(wh + quad * 8);
      f16x8 bh1 = *(const f16x8*)(wh + 32 + quad * 8);
      f16x8 bl0 = *(const f16x8*)(wl + quad * 8);
      f16x8 bl1 = *(const f16x8*)(wl + 32 + quad * 8);
      acc[tt] = __builtin_amdgcn_mfma_f32_16x16x32_f16(a0, bh0, acc[tt], 0, 0, 0);
      acc[tt] = __builtin_amdgcn_mfma_f32_16x16x32_f16(a1, bh1, acc[tt], 0, 0, 0);
      acc[tt] = __builtin_amdgcn_mfma_f32_16x16x32_f16(a0, bl0, acc[tt], 0, 0, 0);
      acc[tt] = __builtin_amdgcn_mfma_f32_16x16x32_f16(a1, bl1, acc[tt], 0, 0, 0);
    }
    #pragma unroll
    for (int r = 0; r < 4; ++r) {
      float s = 0.f, d = 0.f;
      #pragma unroll
      for (int tt = 0; tt < 4; ++tt) {
        s = fmaf(acc[tt][r], as2[tt], s);
        d = fmaf(acc[tt][r], ad2[tt], d);
      }
      #pragma unroll
      for (int msk = 8; msk >= 1; msk >>= 1) {
        s += __shfl_xor(s, msk);
        d += __shfl_xor(d, msk);
      }
      int m = m0 + quad * 4 + r;
      if (m < n) {
        if (c == 0) { a_src2[m] = s; a_dst2[m] = d; }
        unsigned char* r0 = hC + (size_t)m * 32;           // plane 0: feats 0-31
        unsigned char* r1 = hC + plane + (size_t)m * 32;   // plane 1: feats 32-63
        r0[c]      = f8(acc[0][r]);
        r0[16 + c] = f8(acc[1][r]);
        r1[c]      = f8(acc[2][r]);
        r1[16 + c] = f8(acc[3][r]);
      }
    }
  }
}

// K7: layer-2 GAT aggregation, two feature-half passes over L2-resident
// 3.2MB planes. Quad-split: 4 lanes x 8B per edge half-row, 16 edges/step.
#define ACC8(HW, EE) do { \
    f32x2 _a = __builtin_amdgcn_cvt_pk_f32_fp8((HW).x, false); \
    f32x2 _b = __builtin_amdgcn_cvt_pk_f32_fp8((HW).x, true); \
    ac0 = fmaf((EE), _a.x, ac0); ac1 = fmaf((EE), _a.y, ac1); \
    ac2 = fmaf((EE), _b.x, ac2); ac3 = fmaf((EE), _b.y, ac3); \
    _a = __builtin_amdgcn_cvt_pk_f32_fp8((HW).y, false); \
    _b = __builtin_amdgcn_cvt_pk_f32_fp8((HW).y, true); \
    ac4 = fmaf((EE), _a.x, ac4); ac5 = fmaf((EE), _a.y, ac5); \
    ac6 = fmaf((EE), _b.x, ac6); ac7 = fmaf((EE), _b.y, ac7); \
  } while (0)

__global__ __launch_bounds__(256) void k_gat2(
    const unsigned char* __restrict__ hC, const float* __restrict__ a_src2,
    const float* __restrict__ a_dst2, const int* __restrict__ rowbeg,
    const int* __restrict__ rowend, const int* __restrict__ csr,
    const float* __restrict__ bias2,
    __half* __restrict__ h2, int n) {
  __shared__ unsigned long long stage[4 * 64];
  int t = threadIdx.x;
  int w = t >> 6, lane = t & 63;
  int node = blockIdx.x * 4 + w;
  if (node >= n) return;
  int beg = iclamp(rowbeg[node], 0, CSRSZ);
  int end = iclamp(rowend[node], beg, CSRSZ);
  float ad = a_dst2[node];
  float asn = a_src2[node];
  int gg = lane >> 2;          // 16 edge slots
  int pp = lane & 3;           // 4 x 8B chunks = 32B half-row
  size_t plane = (size_t)n * 32;
  unsigned long long* st = &stage[w * 64];
  float dn = 0.f;
  float inv = 0.f;
  #pragma unroll
  for (int hh = 0; hh < 2; ++hh) {
    const uint2* hr = (const uint2*)(hC + (size_t)hh * plane);
    float ac0 = 0.f, ac1 = 0.f, ac2 = 0.f, ac3 = 0.f;
    float ac4 = 0.f, ac5 = 0.f, ac6 = 0.f, ac7 = 0.f;
    for (int tb = beg; tb < end; tb += 64) {
      int tc = end - tb; if (tc > 64) tc = 64;
      int s = 0; float ex = 0.f;
      if (lane < tc) {
        s = iclamp(csr[tb + lane], 0, n - 1);
        ex = __expf(leaky(a_src2[s] + ad));
      }
      if (hh == 0) dn += ex;
      st[lane] = ((unsigned long long)(unsigned)s << 32) | (unsigned)__float_as_uint(ex);
      int steps = (tc + 15) >> 4;   // 1..4, wave-uniform
      uint2 hw0, hw1, hw2, hw3;
      float e0, e1, e2, e3;
#define GLD(J, HW, EE) { \
      unsigned long long pk = st[(J) * 16 + gg]; \
      int ss = (int)(pk >> 32); \
      EE = __uint_as_float((unsigned)pk); \
      HW = hr[(size_t)ss * 4 + pp]; }
      // issue all live slots before consuming (one wait window per tile)
      GLD(0, hw0, e0);
      if (steps > 1) GLD(1, hw1, e1);
      if (steps > 2) GLD(2, hw2, e2);
      if (steps > 3) GLD(3, hw3, e3);
#undef GLD
      ACC8(hw0, e0);
      if (steps > 1) ACC8(hw1, e1);
      if (steps > 2) ACC8(hw2, e2);
      if (steps > 3) ACC8(hw3, e3);
    }
    // reduce partial sums across the 16 edge-slot groups (gg): masks 4..32
    #pragma unroll
    for (int m = 4; m <= 32; m <<= 1) {
      ac0 += __shfl_xor(ac0, m); ac1 += __shfl_xor(ac1, m);
      ac2 += __shfl_xor(ac2, m); ac3 += __shfl_xor(ac3, m);
      ac4 += __shfl_xor(ac4, m); ac5 += __shfl_xor(ac5, m);
      ac6 += __shfl_xor(ac6, m); ac7 += __shfl_xor(ac7, m);
    }
    float exs = __expf(leaky(asn + ad));
    if (hh == 0) {
      #pragma unroll
      for (int m = 32; m >= 1; m >>= 1) dn += __shfl_xor(dn, m);
      dn += exs;
      inv = 1.0f / (dn + 1e-16f);
    }
    // self loop half-row (post-reduce; replicated across gg)
    uint2 hs = hr[(size_t)node * 4 + pp];
    ACC8(hs, exs);
    if (gg == 0) {
      const float* b2 = bias2 + hh * 32 + pp * 8;
      __half2 o0 = __float22half2_rn(make_float2(ac0 * inv + b2[0], ac1 * inv + b2[1]));
      __half2 o1 = __float22half2_rn(make_float2(ac2 * inv + b2[2], ac3 * inv + b2[3]));
      __half2 o2 = __float22half2_rn(make_float2(ac4 * inv + b2[4], ac5 * inv + b2[5]));
      __half2 o3 = __float22half2_rn(make_float2(ac6 * inv + b2[6], ac7 * inv + b2[7]));
      uint4 pk;
      pk.x = *(unsigned*)&o0; pk.y = *(unsigned*)&o1;
      pk.z = *(unsigned*)&o2; pk.w = *(unsigned*)&o3;
      ((uint4*)(h2 + (size_t)node * 64 + hh * 32))[pp] = pk;
    }
  }
}

// K7b: mean pool. One wave per 64 contiguous nodes (lane = feature).
__global__ __launch_bounds__(256) void k_pool(
    const __half* __restrict__ h2, const int* __restrict__ batch,
    float* __restrict__ pool, float* __restrict__ cnt, int n, int G) {
  const int PW = 64;
  int wave = blockIdx.x * 4 + (threadIdx.x >> 6);
  int lane = threadIdx.x & 63;
  int start = wave * PW;
  if (start < n) {
    int end = start + PW; if (end > n) end = n;
    int bcur = iclamp(batch[start], 0, G - 1);
    float acc = 0.f, count = 0.f;
    for (int i = start; i < end; ++i) {
      int b = iclamp(batch[i], 0, G - 1);
      if (b != bcur) {
        atomicAdd(&pool[bcur * 64 + lane], acc);
        if (lane == 0) atomicAdd(&cnt[bcur], count);
        bcur = b; acc = 0.f; count = 0.f;
      }
      acc += __half2float(h2[(size_t)i * 64 + lane]);
      count += 1.f;
    }
    atomicAdd(&pool[bcur * 64 + lane], acc);
    if (lane == 0) atomicAdd(&cnt[bcur], count);
  }
}

// K8: out[g][j] = pool / max(count,1), float32 out.
__global__ void k_final(const float* __restrict__ pool, const float* __restrict__ cnt,
                        float* __restrict__ out, int G) {
  int i = blockIdx.x * blockDim.x + threadIdx.x;
  if (i >= G * 64) return;
  out[i] = pool[i] / fmaxf(cnt[i >> 6], 1.0f);
}

extern "C" void kernel_launch(void* const* d_in, const int* in_sizes, int n_in,
                              void* d_out, int out_size, void* d_ws, size_t ws_size,
                              hipStream_t stream) {
  const float* x        = (const float*)d_in[0];
  const int*   ei       = (const int*)d_in[1];
  const int*   batch    = (const int*)d_in[2];
  const float* W1       = (const float*)d_in[3];
  const float* att_src1 = (const float*)d_in[4];
  const float* att_dst1 = (const float*)d_in[5];
  const float* bias1    = (const float*)d_in[6];
  const float* W2       = (const float*)d_in[7];
  const float* att_src2 = (const float*)d_in[8];
  const float* att_dst2 = (const float*)d_in[9];
  const float* bias2    = (const float*)d_in[10];

  const int n = in_sizes[0] / 4;
  const int E = in_sizes[1] / 2;
  const int G = out_size / 64;

  char* p = (char*)d_ws;
  auto alloc = [&](size_t bytes) -> void* {
    void* r = (void*)p;
    p += (bytes + 255) & ~(size_t)255;
    return r;
  };
  // P: pairs, then csr (same buffer; per-bucket window, barrier-protected).
  unsigned* pairs = (unsigned*)alloc((size_t)CSRSZ * 4);               // 18.9 MB
  int* csr = (int*)pairs;
  // R: hB fp16 | hC fp8 (two planes) - disjoint from P. h2 reuses hB.
  size_t hsz = (size_t)n * 64 * 2;
  char* R = (char*)alloc(hsz + (size_t)n * 64);                        // 19.2 MB
  __half* hB = (__half*)R;
  __half* h2 = (__half*)R;
  unsigned char* hC = (unsigned char*)(R + hsz);
  uint4* xs     = (uint4*)alloc((size_t)n * 16);                       // 1.6 MB
  int*   rowbeg = (int*)alloc((size_t)n * 4);
  int*   rowend = (int*)alloc((size_t)n * 4);
  size_t poolelems = (size_t)G * 64 + G;
  char*  Z = (char*)alloc(poolelems * 4 + (size_t)NBUCK * 4);
  float* pool = (float*)Z;
  float* cnt  = pool + (size_t)G * 64;
  int*   bcur = (int*)(Z + poolelems * 4);
  float* a_dst1 = (float*)alloc((size_t)n * 2 * 4);
  float* a_src2 = (float*)alloc((size_t)n * 4);
  float* a_dst2 = (float*)alloc((size_t)n * 4);

  hipMemsetAsync(Z, 0, poolelems * 4 + (size_t)NBUCK * 4, stream);

  int NBK = (E + MAXR * 1024 - 1) / (MAXR * 1024);
  if (NBK < 512) NBK = 512;
  int natt = (n + 63) / 64;

  k_scatt<<<NBK + natt, 1024, 0, stream>>>(ei, E, n, bcur, pairs,
                                           x, W1, att_src1, att_dst1, xs, a_dst1, NBK);
  k_bgat1<<<NBUCK, 256, 0, stream>>>(pairs, bcur, xs, W1, a_dst1, bias1,
                                     rowbeg, rowend, csr, hB, n);
  k_lin2<<<(n + 255) / 256, 256, 0, stream>>>(hB, W2, att_src2, att_dst2, a_src2, a_dst2, hC, n);
  k_gat2<<<(n + 3) / 4, 256, 0, stream>>>(hC, a_src2, a_dst2, rowbeg, rowend, csr, bias2, h2, n);
  k_pool<<<(n + 255) / 256, 256, 0, stream>>>(h2, batch, pool, cnt, n, G);
  k_final<<<(G * 64 + 255) / 256, 256, 0, stream>>>(pool, cnt, (float*)d_out, G);
}

// Round 8
// 243.903 us; speedup vs baseline: 1.1623x; 1.1623x over previous
//
#include <hip/hip_runtime.h>
#include <hip/hip_bf16.h>
#include <hip/hip_fp16.h>
#include <math.h>

// ---------------------------------------------------------------------------
// 2-layer GAT (PyG GATConv) + global mean pool on MI355X. float32 in/out.
// R26 -> R27: REVERT of the feature-split experiment (it doubled per-edge
// line fetches: 32B used of each 64B line -> FETCH 115->204MB, gat2 59->99us).
//  - k_gat2/k_lin2 back to R24 single-plane form (58.7us measured floor:
//    one fully-used 64B line per edge, ~50% L2 hit, ~2TB/s EA ceiling).
//  - Keeps R25's sound pieces: k_scatt int2 ingest, k_bgat1 praw single
//    global pass (saves 12.8MB re-read).
// ---------------------------------------------------------------------------

__device__ __forceinline__ float leaky(float x) { return x >= 0.f ? x : 0.2f * x; }
__device__ __forceinline__ int iclamp(int v, int lo, int hi) {
  return v < lo ? lo : (v > hi ? hi : v);
}
__device__ __forceinline__ unsigned char f8(float v) {
  return (unsigned char)(__builtin_amdgcn_cvt_pk_fp8_f32(v, v, 0, false) & 0xff);
}
__device__ __forceinline__ float hlo(unsigned w) {
  __half2 h = *(__half2*)&w; return __half2float(h.x);
}
__device__ __forceinline__ float hhi(unsigned w) {
  __half2 h = *(__half2*)&w; return __half2float(h.y);
}

typedef __attribute__((ext_vector_type(8))) _Float16 f16x8;
typedef __attribute__((ext_vector_type(4))) float f32x4;
typedef __attribute__((ext_vector_type(2))) float f32x2;

#define NBUCK 1024
#define BSHIFT 7          // 128 nodes per bucket; valid for n <= 131072
#define BCAP 4608         // per-bucket capacity: mean 4096 + 8 sigma (n=100k)
#define CSRSZ (NBUCK * BCAP)
#define MAXR 8            // max staged edges per thread in scatter
#define SCAP (MAXR * 1024)

// K-A: fused scatter + att1. Blocks [0,NBK): scatter; [NBK, NBK+natt): att1.
__global__ __launch_bounds__(1024, 8) void k_scatt(
    const int* __restrict__ ei, int E, int n, int* __restrict__ bcur,
    unsigned* __restrict__ pairs,
    const float* __restrict__ x, const float* __restrict__ W1,
    const float* __restrict__ att_src1, const float* __restrict__ att_dst1,
    uint4* __restrict__ xs, float* __restrict__ a_dst1, int NBK) {
  __shared__ int h[NBUCK];                 // histogram counts
  __shared__ int cur[NBUCK];               // local placement cursor
  __shared__ int gofs[NBUCK];              // global_base - local_offset
  __shared__ int wtot[16];                 // per-wave scan totals
  __shared__ int htot;                     // grand total
  __shared__ unsigned sstage[SCAP];        // bucket-sorted entries (32KB)
  __shared__ unsigned short sbkt[SCAP];    // bucket id per entry (16KB)
  __shared__ float W1s[256];
  __shared__ float as1[64];
  __shared__ float ad1[64];
  int t = threadIdx.x;
  if (blockIdx.x >= NBK) {
    // ---- att1 part: 64 nodes per block, 16 lanes per node ----
    if (t < 256) W1s[t] = W1[t];
    else if (t >= 256 && t < 320) as1[t - 256] = att_src1[t - 256];
    else if (t >= 320 && t < 384) ad1[t - 320] = att_dst1[t - 320];
    __syncthreads();
    int grp = t >> 4, sub = t & 15;
    int node = (blockIdx.x - NBK) * 64 + grp;
    if (node >= n) return;
    float4 xr = ((const float4*)x)[node];
    float vs = 0.f, vd = 0.f;
    #pragma unroll
    for (int i = 0; i < 4; ++i) {
      int c = sub * 4 + i;
      float hv = xr.x * W1s[c] + xr.y * W1s[64 + c] + xr.z * W1s[128 + c] + xr.w * W1s[192 + c];
      vs = fmaf(hv, as1[c], vs);
      vd = fmaf(hv, ad1[c], vd);
    }
    #pragma unroll
    for (int m = 4; m >= 1; m >>= 1) { vs += __shfl_xor(vs, m); vd += __shfl_xor(vd, m); }
    int wl = t & 63;                       // lane within wave
    float vs1 = __shfl(vs, (wl & 48) + 8); // head1 total (group base + 8)
    float vd1 = __shfl(vd, (wl & 48) + 8);
    if (sub == 0) {
      __half2 x01 = __float22half2_rn(make_float2(xr.x, xr.y));
      __half2 x23 = __float22half2_rn(make_float2(xr.z, xr.w));
      uint4 rec;
      rec.x = *(unsigned*)&x01;
      rec.y = *(unsigned*)&x23;
      rec.z = __float_as_uint(vs);
      rec.w = __float_as_uint(vs1);
      xs[node] = rec;
      ((float2*)a_dst1)[node] = make_float2(vd, vd1);
    }
    return;
  }
  // ---- scatter part ----
  h[t] = 0;
  __syncthreads();
  int chunk = (E + NBK - 1) / NBK;
  chunk = (chunk + 1) & ~1;                // even -> beg stays 8B-aligned
  int beg = blockIdx.x * chunk;
  int end = beg + chunk; if (end > E) end = E;
  unsigned pR[MAXR];
  unsigned short bR[MAXR];
  int cntr = 0;
  for (int i = beg + 2 * t; i < end && cntr < MAXR; i += 2048) {
    if (i + 1 < end) {
      int2 sv = *(const int2*)(ei + i);
      int2 dv = *(const int2*)(ei + E + i);
      {
        int s = iclamp(sv.x, 0, n - 1);
        int d = iclamp(dv.x, 0, n - 1);
        int bkt = d >> BSHIFT;
        pR[cntr] = ((unsigned)(d & 127) << 25) | (unsigned)s;
        bR[cntr] = (unsigned short)bkt;
        atomicAdd(&h[bkt], 1);
        ++cntr;
      }
      if (cntr < MAXR) {
        int s = iclamp(sv.y, 0, n - 1);
        int d = iclamp(dv.y, 0, n - 1);
        int bkt = d >> BSHIFT;
        pR[cntr] = ((unsigned)(d & 127) << 25) | (unsigned)s;
        bR[cntr] = (unsigned short)bkt;
        atomicAdd(&h[bkt], 1);
        ++cntr;
      }
    } else {
      int s = iclamp(ei[i], 0, n - 1);
      int d = iclamp(ei[E + i], 0, n - 1);
      int bkt = d >> BSHIFT;
      pR[cntr] = ((unsigned)(d & 127) << 25) | (unsigned)s;
      bR[cntr] = (unsigned short)bkt;
      atomicAdd(&h[bkt], 1);
      ++cntr;
    }
  }
  __syncthreads();
  int v = h[t];
  // hierarchical inclusive scan: wave-level shfl_up + 16-wave combine
  int lanei = t & 63, wid = t >> 6;
  int sc = v;
  #pragma unroll
  for (int ofs = 1; ofs < 64; ofs <<= 1) {
    int u = __shfl_up(sc, ofs);
    if (lanei >= ofs) sc += u;
  }
  if (lanei == 63) wtot[wid] = sc;
  __syncthreads();
  if (wid == 0 && lanei < 16) {
    int wv = wtot[lanei];
    int s2 = wv;
    #pragma unroll
    for (int ofs = 1; ofs < 16; ofs <<= 1) {
      int u = __shfl_up(s2, ofs);
      if (lanei >= ofs) s2 += u;
    }
    wtot[lanei] = s2 - wv;          // exclusive per-wave offset
  }
  __syncthreads();
  int incl = sc + wtot[wid];        // inclusive scan over 1024 buckets
  int loff = incl - v;              // exclusive local offset
  cur[t] = loff;
  gofs[t] = t * BCAP + (v ? atomicAdd(&bcur[t], v) : 0) - loff;
  if (t == 1023) htot = incl;
  __syncthreads();
  // place entries bucket-sorted into LDS
  for (int k = 0; k < cntr; ++k) {
    int b = bR[k];
    int lpos = atomicAdd(&cur[b], 1);
    sstage[lpos] = pR[k];
    sbkt[lpos] = (unsigned short)b;
  }
  __syncthreads();
  // coalesced flush: consecutive i in same bucket -> consecutive addresses
  int total = htot;
  for (int i = t; i < total; i += 1024) {
    int b = sbkt[i];
    int pos = gofs[b] + i;
    if (pos >= b * BCAP && pos < (b + 1) * BCAP) pairs[pos] = sstage[i];
  }
}

// K-B: fused per-bucket CSR build + layer-1 GAT. One block per bucket.
__global__ __launch_bounds__(256) void k_bgat1(
    const unsigned* __restrict__ pairs, const int* __restrict__ bcur,
    const uint4* __restrict__ xs, const float* __restrict__ W1,
    const float* __restrict__ a_dst1, const float* __restrict__ bias1,
    int* __restrict__ rowbeg, int* __restrict__ rowend, int* __restrict__ csr,
    __half* __restrict__ hB, int n) {
  __shared__ int lcsr[BCAP];
  __shared__ int praw[BCAP];
  __shared__ int sh[128];
  __shared__ int cur[128];
  __shared__ int lrb[128];
  __shared__ int lre[128];
  __shared__ int wt[2];
  __shared__ float W1s[256];
  int t = threadIdx.x;
  W1s[t] = W1[t];
  int b = blockIdx.x;
  int node0 = b << BSHIFT;
  if (node0 >= n) return;  // uniform per block
  int base = b * BCAP;
  int cnt = iclamp(bcur[b], 0, BCAP);
  if (t < 128) sh[t] = 0;
  __syncthreads();
  // single global pass: stage + histogram
  for (int i = t; i < cnt; i += 256) {
    int pv = (int)pairs[base + i];
    praw[i] = pv;
    atomicAdd(&sh[((unsigned)pv) >> 25], 1);
  }
  __syncthreads();
  // hierarchical scan over 128 counts: waves 0,1 via shfl_up + combine
  int v = (t < 128) ? sh[t] : 0;
  int lanei = t & 63, wid = t >> 6;
  int sc = v;
  if (wid < 2) {
    #pragma unroll
    for (int ofs = 1; ofs < 64; ofs <<= 1) {
      int u = __shfl_up(sc, ofs);
      if (lanei >= ofs) sc += u;
    }
    if (lanei == 63) wt[wid] = sc;
  }
  __syncthreads();
  if (t < 128) {
    int off = sc + ((wid == 1) ? wt[0] : 0) - v;  // exclusive
    cur[t] = off;
    lrb[t] = off;
    lre[t] = off + v;
    int node = node0 + t;
    if (node < n) {
      rowbeg[node] = base + off;
      rowend[node] = base + off + v;
    }
  }
  __syncthreads();
  // placement from LDS
  for (int i = t; i < cnt; i += 256) {
    unsigned p = (unsigned)praw[i];
    int l = p >> 25;
    int r = atomicAdd(&cur[l], 1);
    if (r >= 0 && r < BCAP) lcsr[r] = (int)(p & 0x1ffffffu);
  }
  __syncthreads();
  for (int i = t; i < cnt; i += 256)
    csr[base + i] = lcsr[i];    // coalesced flush (csr aliases pairs buffer)
  // ---- gat1 phase: 4 waves x 4 nodes x 16 lanes; 8 rounds = 128 nodes ----
  int wave = t >> 6, lane = t & 63;
  int nd = (lane >> 4), sub = lane & 15;
  for (int rnd = 0; rnd < 8; ++rnd) {
    int nodeLocal = rnd * 16 + wave * 4 + nd;
    int node = node0 + nodeLocal;
    bool valid = node < n;
    int nc = valid ? node : 0;
    int ebeg = valid ? lrb[nodeLocal] : 0;
    int eend = valid ? lre[nodeLocal] : 0;
    ebeg = iclamp(ebeg, 0, BCAP);
    eend = iclamp(eend, ebeg, BCAP);
    float2 ad = ((const float2*)a_dst1)[nc];
    uint4 rs = xs[nc];       // self-loop record: prefetch (independent)
    float A0 = 0.f, A1 = 0.f, A2 = 0.f, A3 = 0.f, dn0 = 0.f;
    float B0 = 0.f, B1 = 0.f, B2 = 0.f, B3 = 0.f, dn1 = 0.f;
    int e = ebeg + sub;
    for (; e + 16 < eend; e += 32) {
      int sa = iclamp(lcsr[e], 0, n - 1);
      int sb = iclamp(lcsr[e + 16], 0, n - 1);
      uint4 ra = xs[sa];
      uint4 rb = xs[sb];
      float ea0 = __expf(leaky(__uint_as_float(ra.z) + ad.x));
      float ea1 = __expf(leaky(__uint_as_float(ra.w) + ad.y));
      float eb0 = __expf(leaky(__uint_as_float(rb.z) + ad.x));
      float eb1 = __expf(leaky(__uint_as_float(rb.w) + ad.y));
      dn0 += ea0 + eb0; dn1 += ea1 + eb1;
      float xa0 = hlo(ra.x), xa1 = hhi(ra.x), xa2 = hlo(ra.y), xa3 = hhi(ra.y);
      float xb0 = hlo(rb.x), xb1 = hhi(rb.x), xb2 = hlo(rb.y), xb3 = hhi(rb.y);
      A0 = fmaf(ea0, xa0, A0); A1 = fmaf(ea0, xa1, A1);
      A2 = fmaf(ea0, xa2, A2); A3 = fmaf(ea0, xa3, A3);
      B0 = fmaf(ea1, xa0, B0); B1 = fmaf(ea1, xa1, B1);
      B2 = fmaf(ea1, xa2, B2); B3 = fmaf(ea1, xa3, B3);
      A0 = fmaf(eb0, xb0, A0); A1 = fmaf(eb0, xb1, A1);
      A2 = fmaf(eb0, xb2, A2); A3 = fmaf(eb0, xb3, A3);
      B0 = fmaf(eb1, xb0, B0); B1 = fmaf(eb1, xb1, B1);
      B2 = fmaf(eb1, xb2, B2); B3 = fmaf(eb1, xb3, B3);
    }
    if (e < eend) {
      int s = iclamp(lcsr[e], 0, n - 1);
      uint4 rr = xs[s];
      float ex0 = __expf(leaky(__uint_as_float(rr.z) + ad.x));
      float ex1 = __expf(leaky(__uint_as_float(rr.w) + ad.y));
      dn0 += ex0; dn1 += ex1;
      float x0 = hlo(rr.x), x1 = hhi(rr.x), x2 = hlo(rr.y), x3 = hhi(rr.y);
      A0 = fmaf(ex0, x0, A0); A1 = fmaf(ex0, x1, A1);
      A2 = fmaf(ex0, x2, A2); A3 = fmaf(ex0, x3, A3);
      B0 = fmaf(ex1, x0, B0); B1 = fmaf(ex1, x1, B1);
      B2 = fmaf(ex1, x2, B2); B3 = fmaf(ex1, x3, B3);
    }
    bool lo = (sub < 8);
    float C0, C1, C2, C3, dnC, sA, sB;
    sA = __shfl_xor(A0, 8); sB = __shfl_xor(B0, 8); C0 = lo ? A0 + sA : B0 + sB;
    sA = __shfl_xor(A1, 8); sB = __shfl_xor(B1, 8); C1 = lo ? A1 + sA : B1 + sB;
    sA = __shfl_xor(A2, 8); sB = __shfl_xor(B2, 8); C2 = lo ? A2 + sA : B2 + sB;
    sA = __shfl_xor(A3, 8); sB = __shfl_xor(B3, 8); C3 = lo ? A3 + sA : B3 + sB;
    sA = __shfl_xor(dn0, 8); sB = __shfl_xor(dn1, 8); dnC = lo ? dn0 + sA : dn1 + sB;
    #pragma unroll
    for (int m = 4; m >= 1; m >>= 1) {
      C0 += __shfl_xor(C0, m); C1 += __shfl_xor(C1, m);
      C2 += __shfl_xor(C2, m); C3 += __shfl_xor(C3, m);
      dnC += __shfl_xor(dnC, m);
    }
    // self loop from the prefetched record
    float exs = __expf(leaky(__uint_as_float(lo ? rs.z : rs.w) + (lo ? ad.x : ad.y)));
    dnC += exs;
    float xs0 = hlo(rs.x), xs1 = hhi(rs.x), xs2 = hlo(rs.y), xs3 = hhi(rs.y);
    C0 = fmaf(exs, xs0, C0); C1 = fmaf(exs, xs1, C1);
    C2 = fmaf(exs, xs2, C2); C3 = fmaf(exs, xs3, C3);
    float inv = 1.0f / (dnC + 1e-16f);
    if (valid) {
      int f0 = sub * 4;
      float vv[4];
      #pragma unroll
      for (int i = 0; i < 4; ++i) {
        int f = f0 + i;
        float accv = C0 * W1s[f] + C1 * W1s[64 + f] + C2 * W1s[128 + f] + C3 * W1s[192 + f];
        float vx = accv * inv + bias1[f];
        vv[i] = vx > 0.f ? vx : expm1f(vx);  // ELU (alpha=1)
      }
      __half2 h01 = __float22half2_rn(make_float2(vv[0], vv[1]));
      __half2 h23 = __float22half2_rn(make_float2(vv[2], vv[3]));
      uint2 pk;
      pk.x = *(unsigned*)&h01;
      pk.y = *(unsigned*)&h23;
      *(uint2*)(hB + (size_t)node * 64 + f0) = pk;
    }
  }
}

// K6 (MFMA fp16): hC = fp8(hB @ W2), plus a_src2/a_dst2 (fp32 exact).
__global__ __launch_bounds__(256) void k_lin2(
    const __half* __restrict__ hB, const float* __restrict__ W2,
    const float* __restrict__ att_src2, const float* __restrict__ att_dst2,
    float* __restrict__ a_src2, float* __restrict__ a_dst2,
    unsigned char* __restrict__ hC, int n) {
  __shared__ __attribute__((aligned(16))) _Float16 Whi[64 * 72];
  __shared__ __attribute__((aligned(16))) _Float16 Wlo[64 * 72];
  int t = threadIdx.x;
  for (int i = t; i < 4096; i += 256) {
    int k = i >> 6, col = i & 63;
    float w = W2[i];
    _Float16 hi = (_Float16)w;
    _Float16 lo = (_Float16)(w - (float)hi);
    Whi[col * 72 + k] = hi;
    Wlo[col * 72 + k] = lo;
  }
  __syncthreads();
  int wave = t >> 6, lane = t & 63;
  int quad = lane >> 4, c = lane & 15;
  float as2[4], ad2[4];
  #pragma unroll
  for (int tt = 0; tt < 4; ++tt) {
    as2[tt] = att_src2[tt * 16 + c];
    ad2[tt] = att_dst2[tt * 16 + c];
  }
  for (int it = 0; it < 4; ++it) {
    int m0 = blockIdx.x * 256 + wave * 64 + it * 16;
    if (m0 >= n) break;
    int mrow = m0 + c; if (mrow > n - 1) mrow = n - 1;
    const _Float16* hrow = (const _Float16*)(hB + (size_t)mrow * 64);
    f16x8 a0 = *(const f16x8*)(hrow + quad * 8);
    f16x8 a1 = *(const f16x8*)(hrow + 32 + quad * 8);
    f32x4 zero = {0.f, 0.f, 0.f, 0.f};
    f32x4 acc[4] = {zero, zero, zero, zero};
    #pragma unroll
    for (int tt = 0; tt < 4; ++tt) {
      int nn = tt * 16 + c;
      const _Float16* wh = &Whi[nn * 72];
      const _Float16* wl = &Wlo[nn * 72];
      f16x8 bh0 = *(const f16x8*)(wh + quad * 8);
      f16x8 bh1 = *(const f16x8*)(wh + 32 + quad * 8);
      f16x8 bl0 = *(const f16x8*)(wl + quad * 8);
      f16x8 bl1 = *(const f16x8*)(wl + 32 + quad * 8);
      acc[tt] = __builtin_amdgcn_mfma_f32_16x16x32_f16(a0, bh0, acc[tt], 0, 0, 0);
      acc[tt] = __builtin_amdgcn_mfma_f32_16x16x32_f16(a1, bh1, acc[tt], 0, 0, 0);
      acc[tt] = __builtin_amdgcn_mfma_f32_16x16x32_f16(a0, bl0, acc[tt], 0, 0, 0);
      acc[tt] = __builtin_amdgcn_mfma_f32_16x16x32_f16(a1, bl1, acc[tt], 0, 0, 0);
    }
    #pragma unroll
    for (int r = 0; r < 4; ++r) {
      float s = 0.f, d = 0.f;
      #pragma unroll
      for (int tt = 0; tt < 4; ++tt) {
        s = fmaf(acc[tt][r], as2[tt], s);
        d = fmaf(acc[tt][r], ad2[tt], d);
      }
      #pragma unroll
      for (int msk = 8; msk >= 1; msk >>= 1) {
        s += __shfl_xor(s, msk);
        d += __shfl_xor(d, msk);
      }
      int m = m0 + quad * 4 + r;
      if (m < n) {
        if (c == 0) { a_src2[m] = s; a_dst2[m] = d; }
        unsigned char* orow = hC + (size_t)m * 64;
        #pragma unroll
        for (int tt = 0; tt < 4; ++tt)
          orow[tt * 16 + c] = f8(acc[tt][r]);
      }
    }
  }
}

// K7: layer-2 GAT aggregation, oct-split + LDS staging, fp8 gather (8B/lane).
// R20 form (4-deep pipeline) -- measured floor: one 64B line per edge.
#define ACC8(HW, EE) do { \
    f32x2 _a = __builtin_amdgcn_cvt_pk_f32_fp8((HW).x, false); \
    f32x2 _b = __builtin_amdgcn_cvt_pk_f32_fp8((HW).x, true); \
    ac0 = fmaf((EE), _a.x, ac0); ac1 = fmaf((EE), _a.y, ac1); \
    ac2 = fmaf((EE), _b.x, ac2); ac3 = fmaf((EE), _b.y, ac3); \
    _a = __builtin_amdgcn_cvt_pk_f32_fp8((HW).y, false); \
    _b = __builtin_amdgcn_cvt_pk_f32_fp8((HW).y, true); \
    ac4 = fmaf((EE), _a.x, ac4); ac5 = fmaf((EE), _a.y, ac5); \
    ac6 = fmaf((EE), _b.x, ac6); ac7 = fmaf((EE), _b.y, ac7); \
  } while (0)

__global__ __launch_bounds__(256) void k_gat2(
    const unsigned char* __restrict__ hC, const float* __restrict__ a_src2,
    const float* __restrict__ a_dst2, const int* __restrict__ rowbeg,
    const int* __restrict__ rowend, const int* __restrict__ csr,
    const float* __restrict__ bias2,
    __half* __restrict__ h2, int n) {
  __shared__ unsigned long long stage[4 * 64];
  int t = threadIdx.x;
  int w = t >> 6, lane = t & 63;
  int node = blockIdx.x * 4 + w;
  if (node >= n) return;
  int beg = iclamp(rowbeg[node], 0, CSRSZ);
  int end = iclamp(rowend[node], beg, CSRSZ);
  float ad = a_dst2[node];
  int g = lane >> 3;
  int p = lane & 7;
  const uint2* hrows = (const uint2*)hC;
  unsigned long long* st = &stage[w * 64];
  float ac0 = 0.f, ac1 = 0.f, ac2 = 0.f, ac3 = 0.f;
  float ac4 = 0.f, ac5 = 0.f, ac6 = 0.f, ac7 = 0.f;
  float dn = 0.f;
  for (int tb = beg; tb < end; tb += 64) {
    int tc = end - tb; if (tc > 64) tc = 64;
    int s = 0; float ex = 0.f;
    if (lane < tc) {
      s = iclamp(csr[tb + lane], 0, n - 1);
      ex = __expf(leaky(a_src2[s] + ad));
    }
    dn += ex;
    st[lane] = ((unsigned long long)(unsigned)s << 32) | (unsigned)__float_as_uint(ex);
    int steps = (tc + 7) >> 3;
    int j = 0;
    for (; j + 4 <= steps; j += 4) {
      unsigned long long pk0 = st[(j + 0) * 8 + g];
      unsigned long long pk1 = st[(j + 1) * 8 + g];
      unsigned long long pk2 = st[(j + 2) * 8 + g];
      unsigned long long pk3 = st[(j + 3) * 8 + g];
      int s0 = (int)(pk0 >> 32), s1 = (int)(pk1 >> 32);
      int s2 = (int)(pk2 >> 32), s3 = (int)(pk3 >> 32);
      float e0 = __uint_as_float((unsigned)pk0);
      float e1 = __uint_as_float((unsigned)pk1);
      float e2 = __uint_as_float((unsigned)pk2);
      float e3 = __uint_as_float((unsigned)pk3);
      // issue all 4 row gathers before consuming (4-deep vmcnt pipeline)
      uint2 hw0 = hrows[(size_t)s0 * 8 + p];
      uint2 hw1 = hrows[(size_t)s1 * 8 + p];
      uint2 hw2 = hrows[(size_t)s2 * 8 + p];
      uint2 hw3 = hrows[(size_t)s3 * 8 + p];
      ACC8(hw0, e0);
      ACC8(hw1, e1);
      ACC8(hw2, e2);
      ACC8(hw3, e3);
    }
    for (; j < steps; ++j) {
      unsigned long long pk0 = st[j * 8 + g];
      int s0 = (int)(pk0 >> 32);
      float e0 = __uint_as_float((unsigned)pk0);
      uint2 hw0 = hrows[(size_t)s0 * 8 + p];
      ACC8(hw0, e0);
    }
  }
  #pragma unroll
  for (int m = 8; m <= 32; m <<= 1) {
    ac0 += __shfl_xor(ac0, m); ac1 += __shfl_xor(ac1, m);
    ac2 += __shfl_xor(ac2, m); ac3 += __shfl_xor(ac3, m);
    ac4 += __shfl_xor(ac4, m); ac5 += __shfl_xor(ac5, m);
    ac6 += __shfl_xor(ac6, m); ac7 += __shfl_xor(ac7, m);
  }
  #pragma unroll
  for (int m = 32; m >= 1; m >>= 1) dn += __shfl_xor(dn, m);
  float exs = __expf(leaky(a_src2[node] + ad));
  dn += exs;
  uint2 hs = hrows[(size_t)node * 8 + p];
  ACC8(hs, exs);
  if (g == 0) {
    float inv = 1.0f / (dn + 1e-16f);
    const float* b2 = bias2 + p * 8;
    __half2 o0 = __float22half2_rn(make_float2(ac0 * inv + b2[0], ac1 * inv + b2[1]));
    __half2 o1 = __float22half2_rn(make_float2(ac2 * inv + b2[2], ac3 * inv + b2[3]));
    __half2 o2 = __float22half2_rn(make_float2(ac4 * inv + b2[4], ac5 * inv + b2[5]));
    __half2 o3 = __float22half2_rn(make_float2(ac6 * inv + b2[6], ac7 * inv + b2[7]));
    uint4 pk;
    pk.x = *(unsigned*)&o0; pk.y = *(unsigned*)&o1;
    pk.z = *(unsigned*)&o2; pk.w = *(unsigned*)&o3;
    ((uint4*)(h2 + (size_t)node * 64))[p] = pk;
  }
}

// K7b: mean pool. One wave per 64 contiguous nodes (lane = feature).
__global__ __launch_bounds__(256) void k_pool(
    const __half* __restrict__ h2, const int* __restrict__ batch,
    float* __restrict__ pool, float* __restrict__ cnt, int n, int G) {
  const int PW = 64;
  int wave = blockIdx.x * 4 + (threadIdx.x >> 6);
  int lane = threadIdx.x & 63;
  int start = wave * PW;
  if (start < n) {
    int end = start + PW; if (end > n) end = n;
    int bcur = iclamp(batch[start], 0, G - 1);
    float acc = 0.f, count = 0.f;
    for (int i = start; i < end; ++i) {
      int b = iclamp(batch[i], 0, G - 1);
      if (b != bcur) {
        atomicAdd(&pool[bcur * 64 + lane], acc);
        if (lane == 0) atomicAdd(&cnt[bcur], count);
        bcur = b; acc = 0.f; count = 0.f;
      }
      acc += __half2float(h2[(size_t)i * 64 + lane]);
      count += 1.f;
    }
    atomicAdd(&pool[bcur * 64 + lane], acc);
    if (lane == 0) atomicAdd(&cnt[bcur], count);
  }
}

// K8: out[g][j] = pool / max(count,1), float32 out.
__global__ void k_final(const float* __restrict__ pool, const float* __restrict__ cnt,
                        float* __restrict__ out, int G) {
  int i = blockIdx.x * blockDim.x + threadIdx.x;
  if (i >= G * 64) return;
  out[i] = pool[i] / fmaxf(cnt[i >> 6], 1.0f);
}

extern "C" void kernel_launch(void* const* d_in, const int* in_sizes, int n_in,
                              void* d_out, int out_size, void* d_ws, size_t ws_size,
                              hipStream_t stream) {
  const float* x        = (const float*)d_in[0];
  const int*   ei       = (const int*)d_in[1];
  const int*   batch    = (const int*)d_in[2];
  const float* W1       = (const float*)d_in[3];
  const float* att_src1 = (const float*)d_in[4];
  const float* att_dst1 = (const float*)d_in[5];
  const float* bias1    = (const float*)d_in[6];
  const float* W2       = (const float*)d_in[7];
  const float* att_src2 = (const float*)d_in[8];
  const float* att_dst2 = (const float*)d_in[9];
  const float* bias2    = (const float*)d_in[10];

  const int n = in_sizes[0] / 4;
  const int E = in_sizes[1] / 2;
  const int G = out_size / 64;

  char* p = (char*)d_ws;
  auto alloc = [&](size_t bytes) -> void* {
    void* r = (void*)p;
    p += (bytes + 255) & ~(size_t)255;
    return r;
  };
  // P: pairs, then csr (same buffer; per-bucket window, barrier-protected).
  unsigned* pairs = (unsigned*)alloc((size_t)CSRSZ * 4);               // 18.9 MB
  int* csr = (int*)pairs;
  // R: hB fp16 | hC fp8 - disjoint from P. h2 reuses hB (dead after lin2).
  size_t hsz = (size_t)n * 64 * 2;
  char* R = (char*)alloc(hsz + (size_t)n * 64);                        // 19.2 MB
  __half* hB = (__half*)R;
  __half* h2 = (__half*)R;
  unsigned char* hC = (unsigned char*)(R + hsz);
  uint4* xs     = (uint4*)alloc((size_t)n * 16);                       // 1.6 MB
  int*   rowbeg = (int*)alloc((size_t)n * 4);
  int*   rowend = (int*)alloc((size_t)n * 4);
  size_t poolelems = (size_t)G * 64 + G;
  char*  Z = (char*)alloc(poolelems * 4 + (size_t)NBUCK * 4);
  float* pool = (float*)Z;
  float* cnt  = pool + (size_t)G * 64;
  int*   bcur = (int*)(Z + poolelems * 4);
  float* a_dst1 = (float*)alloc((size_t)n * 2 * 4);
  float* a_src2 = (float*)alloc((size_t)n * 4);
  float* a_dst2 = (float*)alloc((size_t)n * 4);

  hipMemsetAsync(Z, 0, poolelems * 4 + (size_t)NBUCK * 4, stream);

  int NBK = (E + MAXR * 1024 - 1) / (MAXR * 1024);
  if (NBK < 512) NBK = 512;
  int natt = (n + 63) / 64;

  k_scatt<<<NBK + natt, 1024, 0, stream>>>(ei, E, n, bcur, pairs,
                                           x, W1, att_src1, att_dst1, xs, a_dst1, NBK);
  k_bgat1<<<NBUCK, 256, 0, stream>>>(pairs, bcur, xs, W1, a_dst1, bias1,
                                     rowbeg, rowend, csr, hB, n);
  k_lin2<<<(n + 255) / 256, 256, 0, stream>>>(hB, W2, att_src2, att_dst2, a_src2, a_dst2, hC, n);
  k_gat2<<<(n + 3) / 4, 256, 0, stream>>>(hC, a_src2, a_dst2, rowbeg, rowend, csr, bias2, h2, n);
  k_pool<<<(n + 255) / 256, 256, 0, stream>>>(h2, batch, pool, cnt, n, G);
  k_final<<<(G * 64 + 255) / 256, 256, 0, stream>>>(pool, cnt, (float*)d_out, G);
}